// Round 1
// baseline (3625.105 us; speedup 1.0000x reference)
//
#include <hip/hip_runtime.h>
#include <cstdint>
#include <cstddef>

// Problem constants
#define T_SEQ   128
#define BATCH   16
#define NINP_   1024
#define NHID_   1024
#define NTOK    50257
#define NGATE   4096                     // 4*NHID
#define NROWS   2048                     // T*B
static const size_t LOGITS_SZ = (size_t)NROWS * NTOK;   // 102,926,336 floats

typedef short  short8 __attribute__((ext_vector_type(8)));
typedef float  f32x4  __attribute__((ext_vector_type(4)));

static __device__ __forceinline__ unsigned short f2bf(float f) {
  union { float f; unsigned int u; } v; v.f = f;
  unsigned int u = v.u + 0x7fffu + ((v.u >> 16) & 1u);   // round-to-nearest-even
  return (unsigned short)(u >> 16);
}

// ---------------------------------------------------------------------------
// Embedding gather + fp32 -> bf16 cast.  One block per (t,b) row.
__global__ __launch_bounds__(256) void embed_kernel(
    const int* __restrict__ tokens, const float* __restrict__ embW,
    unsigned short* __restrict__ X0) {
  int row = blockIdx.x;                       // t*16 + b
  int tok = tokens[row];
  int col = threadIdx.x * 4;
  float4 v = *(const float4*)(embW + (size_t)tok * NINP_ + col);
  ushort4 o; o.x = f2bf(v.x); o.y = f2bf(v.y); o.z = f2bf(v.z); o.w = f2bf(v.w);
  *(ushort4*)(X0 + (size_t)row * NINP_ + col) = o;
}

// fp32 -> bf16 bulk convert (Whh weights), 4 elems/thread
__global__ __launch_bounds__(256) void f32_to_bf16_kernel(
    const float* __restrict__ src, unsigned short* __restrict__ dst) {
  size_t i = ((size_t)blockIdx.x * 256 + threadIdx.x) * 4;
  float4 v = *(const float4*)(src + i);
  ushort4 o; o.x = f2bf(v.x); o.y = f2bf(v.y); o.z = f2bf(v.z); o.w = f2bf(v.w);
  *(ushort4*)(dst + i) = o;
}

// ---------------------------------------------------------------------------
// C[M,N] = A_bf16[M,K] @ B_f32[N,K]^T + bias1 + bias2
// 128x128 tile, BK=64, 4 waves in 2x2, each wave 4x4 grid of 16x16x32 MFMAs.
// B is converted fp32->bf16 during LDS staging. N guarded (decoder tail).
__global__ __launch_bounds__(256, 2) void gemm_bt(
    const unsigned short* __restrict__ A,   // [M][K] bf16
    const float* __restrict__ B,            // [N][K] f32
    const float* __restrict__ bias1,        // [N] or null
    const float* __restrict__ bias2,        // [N] or null
    float* __restrict__ Cout,               // [M][Nfull]
    int Mtiles, int Nfull, int K) {
  __shared__ __align__(16) unsigned short As[128][72];   // +8 pad: 144B stride
  __shared__ __align__(16) unsigned short Bs[128][72];
  int tid  = threadIdx.x;
  int bm   = blockIdx.x % Mtiles;
  int bn   = blockIdx.x / Mtiles;          // M fast dim: same-N blocks adjacent (L2/L3 reuse of B)
  int m0 = bm * 128, n0 = bn * 128;
  int wave = tid >> 6, lane = tid & 63, quad = lane >> 4, l15 = lane & 15;
  int wm = (wave >> 1) * 64, wn = (wave & 1) * 64;

  f32x4 acc[4][4];
#pragma unroll
  for (int mi = 0; mi < 4; ++mi)
#pragma unroll
    for (int ni = 0; ni < 4; ++ni) acc[mi][ni] = (f32x4){0.f, 0.f, 0.f, 0.f};

  int KT = K >> 6;
  for (int kt = 0; kt < KT; ++kt) {
    int kbase = kt * 64;
    // stage A: 128x64 bf16, 8 bf16 (16B) per thread x4
#pragma unroll
    for (int it = 0; it < 4; ++it) {
      int idx = it * 256 + tid;
      int row = idx >> 3, c8 = (idx & 7) * 8;
      *(uint4*)&As[row][c8] =
          *(const uint4*)(A + (size_t)(m0 + row) * K + kbase + c8);
    }
    // stage B: 128x64 fp32 -> bf16, float4 per thread x8, guard N
#pragma unroll
    for (int it = 0; it < 8; ++it) {
      int idx = it * 256 + tid;
      int row = idx >> 4, c4 = (idx & 15) * 4;
      int n = n0 + row;
      ushort4 o;
      if (n < Nfull) {
        float4 v = *(const float4*)(B + (size_t)n * K + kbase + c4);
        o.x = f2bf(v.x); o.y = f2bf(v.y); o.z = f2bf(v.z); o.w = f2bf(v.w);
      } else { o.x = 0; o.y = 0; o.z = 0; o.w = 0; }
      *(ushort4*)&Bs[row][c4] = o;
    }
    __syncthreads();
#pragma unroll
    for (int kk = 0; kk < 64; kk += 32) {
      short8 af[4], bfr[4];
#pragma unroll
      for (int mi = 0; mi < 4; ++mi)
        af[mi] = *(const short8*)&As[wm + mi * 16 + l15][kk + quad * 8];
#pragma unroll
      for (int ni = 0; ni < 4; ++ni)
        bfr[ni] = *(const short8*)&Bs[wn + ni * 16 + l15][kk + quad * 8];
#pragma unroll
      for (int mi = 0; mi < 4; ++mi)
#pragma unroll
        for (int ni = 0; ni < 4; ++ni)
          acc[mi][ni] = __builtin_amdgcn_mfma_f32_16x16x32_bf16(
              af[mi], bfr[ni], acc[mi][ni], 0, 0, 0);
    }
    __syncthreads();
  }
  // epilogue: C/D layout col=lane&15 (N), row=quad*4+reg (M)  [m89-verified]
#pragma unroll
  for (int ni = 0; ni < 4; ++ni) {
    int n = n0 + wn + ni * 16 + l15;
    if (n >= Nfull) continue;
    float bs = 0.f;
    if (bias1) bs += bias1[n];
    if (bias2) bs += bias2[n];
#pragma unroll
    for (int mi = 0; mi < 4; ++mi) {
      int m = m0 + wm + mi * 16 + quad * 4;
#pragma unroll
      for (int r = 0; r < 4; ++r)
        Cout[(size_t)(m + r) * Nfull + n] = acc[mi][ni][r] + bs;
    }
  }
}

// ---------------------------------------------------------------------------
// One LSTM time step. 256 blocks x 64 threads (1 wave). Block b owns hidden
// units j0..j0+3: computes their 16 gate rows x 16 batch via one chained
// 16x16x32 MFMA (K=1024), then activations + c/h update fused. No cross-block
// dependency inside a step; step ordering via kernel launch boundaries.
__global__ __launch_bounds__(64) void lstm_step(
    const unsigned short* __restrict__ Whh,   // [4096][1024] bf16
    const float* __restrict__ xw,             // [2048][4096] fp32
    const unsigned short* __restrict__ hin,   // [16][1024] bf16
    unsigned short* __restrict__ hout,        // [16][1024] bf16
    float* __restrict__ cbuf,                 // [16][1024] fp32 (owned slices)
    unsigned short* __restrict__ y,           // [2048][1024] bf16 layer output
    int t, int write_final,
    float* __restrict__ hT, float* __restrict__ cT) {
  int lane = threadIdx.x;
  int quad = lane >> 4, l15 = lane & 15;
  int j0 = blockIdx.x * 4;

  // A-frag: m=l15 -> gate=m>>2, unit=m&3; row in Whh = gate*1024 + j0 + unit
  int arow = (l15 >> 2) * NHID_ + j0 + (l15 & 3);
  const unsigned short* aptr = Whh + (size_t)arow * NHID_ + quad * 8;
  const unsigned short* bptr = hin + (size_t)l15 * NHID_ + quad * 8;

  f32x4 acc = (f32x4){0.f, 0.f, 0.f, 0.f};
#pragma unroll 8
  for (int ks = 0; ks < 32; ++ks) {
    short8 a = *(const short8*)(aptr + ks * 32);
    short8 b = *(const short8*)(bptr + ks * 32);
    acc = __builtin_amdgcn_mfma_f32_16x16x32_bf16(a, b, acc, 0, 0, 0);
  }

  // D: row m = quad*4+r -> gate=quad, unit=r; col n = l15 = batch
  int n = l15;
  float4 x4 = *(const float4*)(xw + ((size_t)(t * BATCH + n)) * NGATE +
                               quad * NHID_ + j0);
  const float* x4p = (const float*)&x4;
  __shared__ float G[4][4][16];   // [gate][unit][batch]
#pragma unroll
  for (int r = 0; r < 4; ++r) {
    float v = acc[r] + x4p[r];
    float a = (quad == 2) ? tanhf(v) : 1.f / (1.f + __expf(-v));
    G[quad][r][n] = a;
  }
  __syncthreads();

  int u = lane >> 4;      // unit 0..3
  int b = lane & 15;      // batch
  int j = j0 + u;
  float i_ = G[0][u][b], f_ = G[1][u][b], g_ = G[2][u][b], o_ = G[3][u][b];
  size_t cidx = (size_t)b * NHID_ + j;
  float cn = f_ * cbuf[cidx] + i_ * g_;
  cbuf[cidx] = cn;
  float hn = o_ * tanhf(cn);
  unsigned short hb = f2bf(hn);
  hout[cidx] = hb;
  y[((size_t)(t * BATCH + b)) * NHID_ + j] = hb;
  if (write_final) { hT[cidx] = hn; cT[cidx] = cn; }
}

// ---------------------------------------------------------------------------
// In-place log_softmax per row of [2048, 50257]
__global__ __launch_bounds__(256) void logsoftmax_kernel(float* __restrict__ out) {
  int row = blockIdx.x;
  float* p = out + (size_t)row * NTOK;
  __shared__ float red[256];
  int tid = threadIdx.x;
  float m = -3.4e38f;
  for (int i = tid; i < NTOK; i += 256) m = fmaxf(m, p[i]);
  red[tid] = m; __syncthreads();
  for (int o = 128; o > 0; o >>= 1) {
    if (tid < o) red[tid] = fmaxf(red[tid], red[tid + o]);
    __syncthreads();
  }
  m = red[0]; __syncthreads();
  float s = 0.f;
  for (int i = tid; i < NTOK; i += 256) s += __expf(p[i] - m);
  red[tid] = s; __syncthreads();
  for (int o = 128; o > 0; o >>= 1) {
    if (tid < o) red[tid] += red[tid + o];
    __syncthreads();
  }
  float lse = m + __logf(red[0]);
  for (int i = tid; i < NTOK; i += 256) p[i] -= lse;
}

// ---------------------------------------------------------------------------
extern "C" void kernel_launch(void* const* d_in, const int* in_sizes, int n_in,
                              void* d_out, int out_size, void* d_ws, size_t ws_size,
                              hipStream_t stream) {
  const int*   tokens = (const int*)d_in[0];
  const float* embW   = (const float*)d_in[1];
  const float* Wih    = (const float*)d_in[2];
  const float* Whh    = (const float*)d_in[3];
  const float* bih    = (const float*)d_in[4];
  const float* bhh    = (const float*)d_in[5];
  const float* decW   = (const float*)d_in[6];
  const float* decb   = (const float*)d_in[7];
  float* out = (float*)d_out;

  // workspace layout (bytes)
  char* w = (char*)d_ws;
  unsigned short* H0   = (unsigned short*)(w);                       // 32 KB
  unsigned short* H1   = (unsigned short*)(w + 32768);               // 32 KB
  float*          Cbuf = (float*)(w + 65536);                        // 64 KB
  unsigned short* X0   = (unsigned short*)(w + 131072);              // 4 MB
  unsigned short* Y1   = (unsigned short*)(w + 131072 + 4194304);    // 4 MB
  unsigned short* Y2   = (unsigned short*)(w + 131072 + 2 * 4194304);// 4 MB
  unsigned short* WhhB = (unsigned short*)(w + 131072 + 3 * 4194304);// 16 MB
  float*          XW   = (float*)(w + 131072 + 3 * 4194304 + 16777216); // 32 MB

  embed_kernel<<<NROWS, 256, 0, stream>>>(tokens, embW, X0);
  f32_to_bf16_kernel<<<8192, 256, 0, stream>>>(Whh, WhhB);  // 2*4096*1024 elems

  for (int l = 0; l < 2; ++l) {
    hipMemsetAsync(w, 0, 131072, stream);   // zero H0,H1,Cbuf
    const unsigned short* Xin = (l == 0) ? X0 : Y1;
    unsigned short* Yout = (l == 0) ? Y1 : Y2;
    gemm_bt<<<16 * 32, 256, 0, stream>>>(
        Xin, Wih + (size_t)l * NGATE * NINP_,
        bih + l * NGATE, bhh + l * NGATE, XW, 16, NGATE, NINP_);
    float* hTp = out + LOGITS_SZ + (size_t)l * BATCH * NHID_;
    float* cTp = out + LOGITS_SZ + 2 * BATCH * NHID_ + (size_t)l * BATCH * NHID_;
    for (int t = 0; t < T_SEQ; ++t) {
      const unsigned short* hin = (t & 1) ? H1 : H0;
      unsigned short*      hout = (t & 1) ? H0 : H1;
      lstm_step<<<256, 64, 0, stream>>>(
          WhhB + (size_t)l * NGATE * NHID_, XW, hin, hout, Cbuf, Yout,
          t, (t == T_SEQ - 1) ? 1 : 0, hTp, cTp);
    }
  }

  gemm_bt<<<16 * 393, 256, 0, stream>>>(
      Y2, decW, decb, (const float*)nullptr, out, 16, NTOK, NINP_);
  logsoftmax_kernel<<<NROWS, 256, 0, stream>>>(out);
}